// Round 1
// baseline (3330.769 us; speedup 1.0000x reference)
//
#include <hip/hip_runtime.h>
#include <hip/hip_bf16.h>
#include <math.h>
#include <stdint.h>

// Problem constants
#define T_TOK 4096
#define H_DIM 2880
#define I_DIM 2880
#define E_NUM 16
#define ALPHA 1.702f
#define EPS_RMS 1e-5f

// GEMM tiling
#define BM 128
#define BN 96          // 6 MFMA col-frags; 2880/96 = 30 col tiles
#define BK 64
#define NKSTEP (H_DIM / BK)   // 45
#define NCT 30
#define MAX_ROWS 18432        // 16384 + 16*127 rounded up to 128
#define MAX_RT 144            // MAX_ROWS/BM
#define GRID_GEMM (MAX_RT * NCT)   // 4320, divisible by 8 (XCD swizzle)

typedef __attribute__((ext_vector_type(8))) short short8;
typedef __attribute__((ext_vector_type(4))) float f32x4;

__device__ __forceinline__ unsigned short f2bf(float f) {
  unsigned u = __float_as_uint(f);
  return (unsigned short)((u + 0x7fffu + ((u >> 16) & 1u)) >> 16);
}
__device__ __forceinline__ unsigned pk2(float a, float b) {
  return (unsigned)f2bf(a) | ((unsigned)f2bf(b) << 16);
}

// ---------------- K1: rmsnorm + residual copy + fp32 gate + top4 ----------------
__global__ __launch_bounds__(256) void k_norm_gate(
    const float* __restrict__ x, const float* __restrict__ norm_w,
    const float* __restrict__ gate_w, const float* __restrict__ gate_b,
    float* __restrict__ out, unsigned short* __restrict__ t_out,
    int* __restrict__ topk_id, float* __restrict__ topk_w,
    int* __restrict__ counts)
{
  int t = blockIdx.x, tid = threadIdx.x;
  const float4* xr = (const float4*)(x + (size_t)t * H_DIM);
  float4* outr = (float4*)(out + (size_t)t * H_DIM);
  float4 xa[3];
  float ss = 0.f;
  int j = 0;
  for (int i = tid; i < 720; i += 256, j++) {
    float4 v = xr[i]; xa[j] = v; outr[i] = v;    // residual: out = x
    ss += v.x * v.x + v.y * v.y + v.z * v.z + v.w * v.w;
  }
#pragma unroll
  for (int o = 1; o < 64; o <<= 1) ss += __shfl_xor(ss, o, 64);
  __shared__ float red[4];
  if ((tid & 63) == 0) red[tid >> 6] = ss;
  __syncthreads();
  float rs = rsqrtf((red[0] + red[1] + red[2] + red[3]) * (1.f / H_DIM) + EPS_RMS);

  float part[16];
#pragma unroll
  for (int q = 0; q < 16; q++) part[q] = 0.f;
  j = 0;
  for (int i = tid; i < 720; i += 256, j++) {
    float4 v = xa[j];
    float4 w = ((const float4*)norm_w)[i];
    float t0 = v.x * rs * w.x, t1 = v.y * rs * w.y;
    float t2 = v.z * rs * w.z, t3 = v.w * rs * w.w;
    ushort4 b; b.x = f2bf(t0); b.y = f2bf(t1); b.z = f2bf(t2); b.w = f2bf(t3);
    ((ushort4*)(t_out + (size_t)t * H_DIM))[i] = b;
#pragma unroll
    for (int q = 0; q < 16; q++) {    // fp32 logits from pre-cast t (selection accuracy)
      float4 g = ((const float4*)(gate_w + (size_t)q * H_DIM))[i];
      part[q] += t0 * g.x + t1 * g.y + t2 * g.z + t3 * g.w;
    }
  }
  __shared__ float lg[4][16];
#pragma unroll
  for (int q = 0; q < 16; q++) {
    float p = part[q];
#pragma unroll
    for (int o = 1; o < 64; o <<= 1) p += __shfl_xor(p, o, 64);
    if ((tid & 63) == 0) lg[tid >> 6][q] = p;
  }
  __syncthreads();
  if (tid == 0) {
    float logit[16];
    for (int q = 0; q < 16; q++)
      logit[q] = lg[0][q] + lg[1][q] + lg[2][q] + lg[3][q] + gate_b[q];
    unsigned used = 0; int idx[4]; float val[4];
    for (int k = 0; k < 4; k++) {           // ties -> lowest index, like lax.top_k
      float best = -3.4e38f; int bi = 0;
      for (int q = 0; q < 16; q++)
        if (!((used >> q) & 1u) && logit[q] > best) { best = logit[q]; bi = q; }
      used |= 1u << bi; idx[k] = bi; val[k] = best;
    }
    float s0 = 0.f, w4[4];
    for (int k = 0; k < 4; k++) { w4[k] = expf(val[k] - val[0]); s0 += w4[k]; }
    for (int k = 0; k < 4; k++) {
      topk_id[t * 4 + k] = idx[k];
      topk_w[t * 4 + k] = w4[k] / s0;
      atomicAdd(&counts[idx[k]], 1);
    }
  }
}

// ---------------- K2a: padded prefix offsets ----------------
__global__ void k_offsets(const int* __restrict__ counts, int* __restrict__ d_off) {
  if (threadIdx.x == 0) {
    int acc = 0;
    for (int q = 0; q < 16; q++) {
      d_off[q] = acc;
      acc += ((counts[q] + BM - 1) / BM) * BM;
    }
    d_off[16] = acc;
  }
}

// ---------------- K2b: deterministic token-ordered routing lists ----------------
__global__ __launch_bounds__(256) void k_fill(
    const int* __restrict__ topk_id, const float* __restrict__ topk_w,
    const int* __restrict__ counts, const int* __restrict__ d_off,
    int* __restrict__ perm_tok, float* __restrict__ perm_w)
{
  int e = blockIdx.x;
  int base = d_off[e], pe = d_off[e + 1] - base, cnt = counts[e];
  int tid = threadIdx.x, lane = tid & 63, wv = tid >> 6;
  __shared__ int wsum[4];
  int pos = 0;
  for (int c0 = 0; c0 < T_TOK; c0 += 256) {
    int tok = c0 + tid;
    int4 ids = ((const int4*)topk_id)[tok];
    int flag = 0, slot = 0;
    if (ids.x == e) { flag = 1; slot = 0; }
    else if (ids.y == e) { flag = 1; slot = 1; }
    else if (ids.z == e) { flag = 1; slot = 2; }
    else if (ids.w == e) { flag = 1; slot = 3; }
    unsigned long long b = __ballot(flag);
    int wprefix = __popcll(b & ((1ULL << lane) - 1ULL));
    if (lane == 0) wsum[wv] = __popcll(b);
    __syncthreads();
    int woff = 0;
    for (int i = 0; i < wv; i++) woff += wsum[i];
    int tot = wsum[0] + wsum[1] + wsum[2] + wsum[3];
    if (flag) {
      int p = base + pos + woff + wprefix;
      perm_tok[p] = tok;
      perm_w[p] = topk_w[tok * 4 + slot];
    }
    pos += tot;
    __syncthreads();
  }
  for (int i = cnt + tid; i < pe; i += 256) {   // padding rows: token 0, weight 0
    perm_tok[base + i] = 0;
    perm_w[base + i] = 0.f;
  }
}

// ---------------- K3: grouped gemm1 (t @ w1^T) + bias + SwiGLU -> act (bf16) ----------------
__global__ __launch_bounds__(256) void k_gemm1(
    const unsigned short* __restrict__ t_bf16,
    const float* __restrict__ w1, const float* __restrict__ b1,
    const int* __restrict__ perm_tok, const int* __restrict__ d_off,
    unsigned short* __restrict__ act)
{
  __shared__ __align__(16) unsigned char lds[40960]; // A 16K | Bg 12K | Bl 12K
  const int total = d_off[16];
  int bid = blockIdx.x;
  int wg = (bid & 7) * (GRID_GEMM / 8) + (bid >> 3);   // XCD-chunked, rt fastest
  int ct = wg / MAX_RT, rt = wg % MAX_RT;
  int rowbase = rt * BM;
  if (rowbase >= total) return;
  int e = 0;
#pragma unroll
  for (int q = 0; q < E_NUM; q++) if (d_off[q + 1] <= rowbase) e = q + 1;

  int tid = threadIdx.x, lane = tid & 63, wv = tid >> 6;

  const uint4* srcA[4]; unsigned dstA[4];
#pragma unroll
  for (int i = 0; i < 4; i++) {
    int c = tid + 256 * i, r = c >> 3, l = c & 7;
    int tok = perm_tok[rowbase + r];
    srcA[i] = (const uint4*)(t_bf16 + (size_t)tok * H_DIM) + (l ^ (r & 7));
    dstA[i] = (unsigned)(r * 128 + l * 16);
  }
  const float4* srcBg[3]; const float4* srcBl[3]; unsigned dstB[3];
#pragma unroll
  for (int i = 0; i < 3; i++) {
    int c = tid + 256 * i, r = c >> 3, l = c & 7;
    size_t rg = (size_t)e * (2 * I_DIM) + (size_t)(ct * BN + r);
    srcBg[i] = (const float4*)(w1 + rg * H_DIM) + 2 * (l ^ (r & 7));
    srcBl[i] = (const float4*)(w1 + (rg + I_DIM) * H_DIM) + 2 * (l ^ (r & 7));
    dstB[i] = (unsigned)(r * 128 + l * 16);
  }

  f32x4 zero = {0.f, 0.f, 0.f, 0.f};
  f32x4 accg[2][6], accl[2][6];
#pragma unroll
  for (int m = 0; m < 2; m++)
#pragma unroll
    for (int n = 0; n < 6; n++) { accg[m][n] = zero; accl[m][n] = zero; }

  unsigned char* A_l = lds;
  unsigned char* Bg_l = lds + 16384;
  unsigned char* Bl_l = lds + 28672;
  int arow0 = wv * 32 + (lane & 15);
  int arow1 = arow0 + 16;

  for (int kk = 0; kk < NKSTEP; kk++) {
    uint4 av[4];
#pragma unroll
    for (int i = 0; i < 4; i++) av[i] = srcA[i][kk * 8];
    float4 g0[3], g1[3], l0[3], l1[3];
#pragma unroll
    for (int i = 0; i < 3; i++) {
      g0[i] = srcBg[i][kk * 16]; g1[i] = srcBg[i][kk * 16 + 1];
      l0[i] = srcBl[i][kk * 16]; l1[i] = srcBl[i][kk * 16 + 1];
    }
    __syncthreads();   // prev compute done before overwrite
#pragma unroll
    for (int i = 0; i < 4; i++) *(uint4*)(A_l + dstA[i]) = av[i];
#pragma unroll
    for (int i = 0; i < 3; i++) {
      uint4 pg, pl;
      pg.x = pk2(g0[i].x, g0[i].y); pg.y = pk2(g0[i].z, g0[i].w);
      pg.z = pk2(g1[i].x, g1[i].y); pg.w = pk2(g1[i].z, g1[i].w);
      pl.x = pk2(l0[i].x, l0[i].y); pl.y = pk2(l0[i].z, l0[i].w);
      pl.z = pk2(l1[i].x, l1[i].y); pl.w = pk2(l1[i].z, l1[i].w);
      *(uint4*)(Bg_l + dstB[i]) = pg;
      *(uint4*)(Bl_l + dstB[i]) = pl;
    }
    __syncthreads();
#pragma unroll
    for (int kf = 0; kf < 2; kf++) {
      int ch = kf * 4 + (lane >> 4);
      short8 a0 = *(const short8*)(A_l + arow0 * 128 + ((ch ^ (arow0 & 7)) * 16));
      short8 a1 = *(const short8*)(A_l + arow1 * 128 + ((ch ^ (arow1 & 7)) * 16));
#pragma unroll
      for (int n = 0; n < 6; n++) {
        int br = n * 16 + (lane & 15);
        int bo = br * 128 + ((ch ^ (br & 7)) * 16);
        short8 bg = *(const short8*)(Bg_l + bo);
        short8 bl = *(const short8*)(Bl_l + bo);
        accg[0][n] = __builtin_amdgcn_mfma_f32_16x16x32_bf16(a0, bg, accg[0][n], 0, 0, 0);
        accg[1][n] = __builtin_amdgcn_mfma_f32_16x16x32_bf16(a1, bg, accg[1][n], 0, 0, 0);
        accl[0][n] = __builtin_amdgcn_mfma_f32_16x16x32_bf16(a0, bl, accl[0][n], 0, 0, 0);
        accl[1][n] = __builtin_amdgcn_mfma_f32_16x16x32_bf16(a1, bl, accl[1][n], 0, 0, 0);
      }
    }
  }

  int colL = lane & 15, rq = lane >> 4;
#pragma unroll
  for (int mi = 0; mi < 2; mi++)
#pragma unroll
    for (int n = 0; n < 6; n++) {
      int col = ct * BN + n * 16 + colL;
      float bgv = b1[(size_t)e * (2 * I_DIM) + col];
      float blv = b1[(size_t)e * (2 * I_DIM) + I_DIM + col];
#pragma unroll
      for (int j = 0; j < 4; j++) {
        float g = accg[mi][n][j] + bgv;
        float lv = accl[mi][n][j] + blv;
        float s = 1.f / (1.f + __expf(-ALPHA * g));
        float av = g * s * (lv + 1.f);
        int row = rowbase + wv * 32 + mi * 16 + rq * 4 + j;
        act[(size_t)row * I_DIM + col] = f2bf(av);
      }
    }
}

// ---------------- K4: grouped gemm2 (act @ w2^T) + bias, weighted scatter ----------------
__global__ __launch_bounds__(256) void k_gemm2(
    const unsigned short* __restrict__ act,
    const float* __restrict__ w2, const float* __restrict__ b2,
    const int* __restrict__ perm_tok, const float* __restrict__ perm_w,
    const int* __restrict__ d_off,
    float* __restrict__ out)
{
  __shared__ __align__(16) unsigned char lds[28672]; // A 16K | B 12K
  __shared__ int stok[128]; __shared__ float swt[128];
  const int total = d_off[16];
  int bid = blockIdx.x;
  int wg = (bid & 7) * (GRID_GEMM / 8) + (bid >> 3);
  int ct = wg / MAX_RT, rt = wg % MAX_RT;
  int rowbase = rt * BM;
  if (rowbase >= total) return;
  int e = 0;
#pragma unroll
  for (int q = 0; q < E_NUM; q++) if (d_off[q + 1] <= rowbase) e = q + 1;

  int tid = threadIdx.x, lane = tid & 63, wv = tid >> 6;
  if (tid < 128) { stok[tid] = perm_tok[rowbase + tid]; swt[tid] = perm_w[rowbase + tid]; }

  const uint4* srcA[4]; unsigned dstA[4];
#pragma unroll
  for (int i = 0; i < 4; i++) {
    int c = tid + 256 * i, r = c >> 3, l = c & 7;
    srcA[i] = (const uint4*)(act + (size_t)(rowbase + r) * I_DIM) + (l ^ (r & 7));
    dstA[i] = (unsigned)(r * 128 + l * 16);
  }
  const float4* srcB[3]; unsigned dstB[3];
#pragma unroll
  for (int i = 0; i < 3; i++) {
    int c = tid + 256 * i, r = c >> 3, l = c & 7;
    srcB[i] = (const float4*)(w2 + ((size_t)e * H_DIM + ct * BN + r) * I_DIM) + 2 * (l ^ (r & 7));
    dstB[i] = (unsigned)(r * 128 + l * 16);
  }

  f32x4 zero = {0.f, 0.f, 0.f, 0.f};
  f32x4 acc[2][6];
#pragma unroll
  for (int m = 0; m < 2; m++)
#pragma unroll
    for (int n = 0; n < 6; n++) acc[m][n] = zero;

  unsigned char* A_l = lds;
  unsigned char* B_l = lds + 16384;
  int arow0 = wv * 32 + (lane & 15);
  int arow1 = arow0 + 16;

  for (int kk = 0; kk < NKSTEP; kk++) {
    uint4 av[4];
#pragma unroll
    for (int i = 0; i < 4; i++) av[i] = srcA[i][kk * 8];
    float4 b0[3], b1v[3];
#pragma unroll
    for (int i = 0; i < 3; i++) { b0[i] = srcB[i][kk * 16]; b1v[i] = srcB[i][kk * 16 + 1]; }
    __syncthreads();
#pragma unroll
    for (int i = 0; i < 4; i++) *(uint4*)(A_l + dstA[i]) = av[i];
#pragma unroll
    for (int i = 0; i < 3; i++) {
      uint4 pb;
      pb.x = pk2(b0[i].x, b0[i].y); pb.y = pk2(b0[i].z, b0[i].w);
      pb.z = pk2(b1v[i].x, b1v[i].y); pb.w = pk2(b1v[i].z, b1v[i].w);
      *(uint4*)(B_l + dstB[i]) = pb;
    }
    __syncthreads();
#pragma unroll
    for (int kf = 0; kf < 2; kf++) {
      int ch = kf * 4 + (lane >> 4);
      short8 a0 = *(const short8*)(A_l + arow0 * 128 + ((ch ^ (arow0 & 7)) * 16));
      short8 a1 = *(const short8*)(A_l + arow1 * 128 + ((ch ^ (arow1 & 7)) * 16));
#pragma unroll
      for (int n = 0; n < 6; n++) {
        int br = n * 16 + (lane & 15);
        int bo = br * 128 + ((ch ^ (br & 7)) * 16);
        short8 bb = *(const short8*)(B_l + bo);
        acc[0][n] = __builtin_amdgcn_mfma_f32_16x16x32_bf16(a0, bb, acc[0][n], 0, 0, 0);
        acc[1][n] = __builtin_amdgcn_mfma_f32_16x16x32_bf16(a1, bb, acc[1][n], 0, 0, 0);
      }
    }
  }

  int colL = lane & 15, rq = lane >> 4;
#pragma unroll
  for (int mi = 0; mi < 2; mi++)
#pragma unroll
    for (int n = 0; n < 6; n++) {
      int col = ct * BN + n * 16 + colL;
      float b2v = b2[(size_t)e * H_DIM + col];
#pragma unroll
      for (int j = 0; j < 4; j++) {
        int rl = wv * 32 + mi * 16 + rq * 4 + j;
        float y = (acc[mi][n][j] + b2v) * swt[rl];
        atomicAdd(out + (size_t)stok[rl] * H_DIM + col, y);
      }
    }
}

// ---------------- launch ----------------
extern "C" void kernel_launch(void* const* d_in, const int* in_sizes, int n_in,
                              void* d_out, int out_size, void* d_ws, size_t ws_size,
                              hipStream_t stream)
{
  const float* x      = (const float*)d_in[0];
  const float* norm_w = (const float*)d_in[1];
  const float* gate_w = (const float*)d_in[2];
  const float* gate_b = (const float*)d_in[3];
  const float* w1     = (const float*)d_in[4];
  const float* b1     = (const float*)d_in[5];
  const float* w2     = (const float*)d_in[6];
  const float* b2     = (const float*)d_in[7];
  float* out = (float*)d_out;
  char* ws = (char*)d_ws;

  // ws layout (≈130.1 MB total)
  unsigned short* t_bf16  = (unsigned short*)(ws);                    // 23,592,960
  unsigned short* act     = (unsigned short*)(ws + 23592960);         // 106,168,320
  int*            topk_id = (int*)(ws + 129761280);                   // 65,536
  float*          topk_w  = (float*)(ws + 129826816);                 // 65,536
  int*            perm_tk = (int*)(ws + 129892352);                   // 73,728
  float*          perm_w  = (float*)(ws + 129966080);                 // 73,728
  int*            counts  = (int*)(ws + 130039808);                   // 64
  int*            d_off   = (int*)(ws + 130039872);                   // 68

  hipMemsetAsync(counts, 0, 64, stream);
  hipLaunchKernelGGL(k_norm_gate, dim3(T_TOK), dim3(256), 0, stream,
                     x, norm_w, gate_w, gate_b, out, t_bf16, topk_id, topk_w, counts);
  hipLaunchKernelGGL(k_offsets, dim3(1), dim3(64), 0, stream, counts, d_off);
  hipLaunchKernelGGL(k_fill, dim3(16), dim3(256), 0, stream,
                     topk_id, topk_w, counts, d_off, perm_tk, perm_w);
  hipLaunchKernelGGL(k_gemm1, dim3(GRID_GEMM), dim3(256), 0, stream,
                     t_bf16, w1, b1, perm_tk, d_off, act);
  hipLaunchKernelGGL(k_gemm2, dim3(GRID_GEMM), dim3(256), 0, stream,
                     act, w2, b2, perm_tk, perm_w, d_off, out);
}

// Round 2
// 1761.595 us; speedup vs baseline: 1.8908x; 1.8908x over previous
//
#include <hip/hip_runtime.h>
#include <hip/hip_bf16.h>
#include <math.h>
#include <stdint.h>

// Problem constants
#define T_TOK 4096
#define H_DIM 2880
#define E_NUM 16
#define ALPHA 1.702f
#define EPS_RMS 1e-5f

// GEMM tiling
#define PADM 192              // BM = row padding granularity
#define BK 32
#define NK (H_DIM / BK)       // 90
#define MAX_RT 104
#define MAX_ROWS (MAX_RT * PADM)   // 19968
#define NCT1 30               // gemm1: 30 col tiles of 96 (x2 halves)
#define NCT2 15               // gemm2: 15 col tiles of 192
#define G1 (MAX_RT * NCT1)    // 3120 (div 8)
#define G2 (MAX_RT * NCT2)    // 1560 (div 8)

typedef __attribute__((ext_vector_type(8))) short short8;
typedef __attribute__((ext_vector_type(4))) float f32x4;

__device__ __forceinline__ unsigned short f2bf(float f) {
  unsigned u = __float_as_uint(f);
  return (unsigned short)((u + 0x7fffu + ((u >> 16) & 1u)) >> 16);
}
__device__ __forceinline__ unsigned pk2(float a, float b) {
  return (unsigned)f2bf(a) | ((unsigned)f2bf(b) << 16);
}
__device__ __forceinline__ void gl_lds16(const void* g, unsigned char* lds_dst) {
  __builtin_amdgcn_global_load_lds(
      (const __attribute__((address_space(1))) void*)g,
      (__attribute__((address_space(3))) void*)lds_dst, 16, 0, 0);
}

// ---------------- K1: rmsnorm + residual copy + fp32 gate + top4 ----------------
__global__ __launch_bounds__(256) void k_norm_gate(
    const float* __restrict__ x, const float* __restrict__ norm_w,
    const float* __restrict__ gate_w, const float* __restrict__ gate_b,
    float* __restrict__ out, unsigned short* __restrict__ t_out,
    int* __restrict__ topk_id, float* __restrict__ topk_w,
    int* __restrict__ counts)
{
  int t = blockIdx.x, tid = threadIdx.x;
  const float4* xr = (const float4*)(x + (size_t)t * H_DIM);
  float4* outr = (float4*)(out + (size_t)t * H_DIM);
  float4 xa[3];
  float ss = 0.f;
  int j = 0;
  for (int i = tid; i < 720; i += 256, j++) {
    float4 v = xr[i]; xa[j] = v; outr[i] = v;    // residual: out = x
    ss += v.x * v.x + v.y * v.y + v.z * v.z + v.w * v.w;
  }
#pragma unroll
  for (int o = 1; o < 64; o <<= 1) ss += __shfl_xor(ss, o, 64);
  __shared__ float red[4];
  if ((tid & 63) == 0) red[tid >> 6] = ss;
  __syncthreads();
  float rs = rsqrtf((red[0] + red[1] + red[2] + red[3]) * (1.f / H_DIM) + EPS_RMS);

  float part[16];
#pragma unroll
  for (int q = 0; q < 16; q++) part[q] = 0.f;
  j = 0;
  for (int i = tid; i < 720; i += 256, j++) {
    float4 v = xa[j];
    float4 w = ((const float4*)norm_w)[i];
    float t0 = v.x * rs * w.x, t1 = v.y * rs * w.y;
    float t2 = v.z * rs * w.z, t3 = v.w * rs * w.w;
    ushort4 b; b.x = f2bf(t0); b.y = f2bf(t1); b.z = f2bf(t2); b.w = f2bf(t3);
    ((ushort4*)(t_out + (size_t)t * H_DIM))[i] = b;
#pragma unroll
    for (int q = 0; q < 16; q++) {    // fp32 logits (selection accuracy)
      float4 g = ((const float4*)(gate_w + (size_t)q * H_DIM))[i];
      part[q] += t0 * g.x + t1 * g.y + t2 * g.z + t3 * g.w;
    }
  }
  __shared__ float lg[4][16];
#pragma unroll
  for (int q = 0; q < 16; q++) {
    float p = part[q];
#pragma unroll
    for (int o = 1; o < 64; o <<= 1) p += __shfl_xor(p, o, 64);
    if ((tid & 63) == 0) lg[tid >> 6][q] = p;
  }
  __syncthreads();
  if (tid == 0) {
    float logit[16];
    for (int q = 0; q < 16; q++)
      logit[q] = lg[0][q] + lg[1][q] + lg[2][q] + lg[3][q] + gate_b[q];
    unsigned used = 0; int idx[4]; float val[4];
    for (int k = 0; k < 4; k++) {           // ties -> lowest index
      float best = -3.4e38f; int bi = 0;
      for (int q = 0; q < 16; q++)
        if (!((used >> q) & 1u) && logit[q] > best) { best = logit[q]; bi = q; }
      used |= 1u << bi; idx[k] = bi; val[k] = best;
    }
    float s0 = 0.f, w4[4];
    for (int k = 0; k < 4; k++) { w4[k] = expf(val[k] - val[0]); s0 += w4[k]; }
    for (int k = 0; k < 4; k++) {
      topk_id[t * 4 + k] = idx[k];
      topk_w[t * 4 + k] = w4[k] / s0;
      atomicAdd(&counts[idx[k]], 1);
    }
  }
}

// ---------------- K2a: padded prefix offsets ----------------
__global__ void k_offsets(const int* __restrict__ counts, int* __restrict__ d_off) {
  if (threadIdx.x == 0) {
    int acc = 0;
    for (int q = 0; q < 16; q++) {
      d_off[q] = acc;
      acc += ((counts[q] + PADM - 1) / PADM) * PADM;
    }
    d_off[16] = acc;
  }
}

// ---------------- K2b: deterministic token-ordered routing lists ----------------
__global__ __launch_bounds__(256) void k_fill(
    const int* __restrict__ topk_id, const float* __restrict__ topk_w,
    const int* __restrict__ counts, const int* __restrict__ d_off,
    int* __restrict__ perm_tok, float* __restrict__ perm_w)
{
  int e = blockIdx.x;
  int base = d_off[e], pe = d_off[e + 1] - base, cnt = counts[e];
  int tid = threadIdx.x, lane = tid & 63, wv = tid >> 6;
  __shared__ int wsum[4];
  int pos = 0;
  for (int c0 = 0; c0 < T_TOK; c0 += 256) {
    int tok = c0 + tid;
    int4 ids = ((const int4*)topk_id)[tok];
    int flag = 0, slot = 0;
    if (ids.x == e) { flag = 1; slot = 0; }
    else if (ids.y == e) { flag = 1; slot = 1; }
    else if (ids.z == e) { flag = 1; slot = 2; }
    else if (ids.w == e) { flag = 1; slot = 3; }
    unsigned long long b = __ballot(flag);
    int wprefix = __popcll(b & ((1ULL << lane) - 1ULL));
    if (lane == 0) wsum[wv] = __popcll(b);
    __syncthreads();
    int woff = 0;
    for (int i = 0; i < wv; i++) woff += wsum[i];
    int tot = wsum[0] + wsum[1] + wsum[2] + wsum[3];
    if (flag) {
      int p = base + pos + woff + wprefix;
      perm_tok[p] = tok;
      perm_w[p] = topk_w[tok * 4 + slot];
    }
    pos += tot;
    __syncthreads();
  }
  for (int i = cnt + tid; i < pe; i += 256) {   // padding rows: token 0, weight 0
    perm_tok[base + i] = 0;
    perm_w[base + i] = 0.f;
  }
}

// ---------------- K3: grouped gemm1 + bias + SwiGLU -> act (bf16) ----------------
// BM=192 (4 waves x 3 m-frags), effective N = 96 gate + 96 lin, BK=32, dbuf LDS.
// LDS: A0@0 A1@12288 B0@24576 B1@36864 (48KB). Rows 64B, chunk swizzle c^((r>>1)&3).
__global__ __launch_bounds__(256, 2) void k_gemm1(
    const unsigned short* __restrict__ t_bf16,
    const float* __restrict__ w1, const float* __restrict__ b1,
    const int* __restrict__ perm_tok, const int* __restrict__ d_off,
    unsigned short* __restrict__ act)
{
  __shared__ __align__(16) unsigned char lds[49152];
  const int total = d_off[16];
  int bid = blockIdx.x;
  int wg = (bid & 7) * (G1 / 8) + (bid >> 3);   // XCD-chunked, rt fastest
  int ct = wg / MAX_RT, rt = wg % MAX_RT;
  int rowbase = rt * PADM;
  if (rowbase >= total) return;
  int e = 0;
#pragma unroll
  for (int q = 0; q < E_NUM; q++) if (d_off[q + 1] <= rowbase) e = q + 1;

  int tid = threadIdx.x, lane = tid & 63, wv = tid >> 6;

  // A staging: global_load_lds, linear LDS dst, pre-swizzled global chunk
  const unsigned short* asrc[3]; unsigned adst[3];
#pragma unroll
  for (int i = 0; i < 3; i++) {
    int cl = tid + 256 * i;                  // 0..767
    int r = cl >> 2, c = cl & 3;
    int cs = c ^ ((r >> 1) & 3);
    int tok = perm_tok[rowbase + r];
    asrc[i] = t_bf16 + (size_t)tok * H_DIM + cs * 8;
    adst[i] = (unsigned)cl * 16;
  }
  // B staging: fp32 -> regs -> bf16 LDS (dst-side swizzle)
  const float4* bsrc[3]; unsigned bdst[3];
#pragma unroll
  for (int j = 0; j < 3; j++) {
    int idx = tid + 256 * j;
    int r = idx >> 2, c = idx & 3;
    size_t grow = (size_t)e * (2 * H_DIM) +
                  (r < 96 ? (size_t)(ct * 96 + r) : (size_t)(H_DIM + ct * 96 + (r - 96)));
    bsrc[j] = (const float4*)(w1 + grow * H_DIM) + c * 2;
    bdst[j] = (unsigned)(24576 + r * 64 + ((c ^ ((r >> 1) & 3)) << 4));
  }

  // LDS fragment read offsets
  int ch = lane >> 4;
  unsigned aoff[3], boff[12];
#pragma unroll
  for (int m = 0; m < 3; m++) {
    int r = wv * 48 + m * 16 + (lane & 15);
    aoff[m] = (unsigned)(r * 64 + ((ch ^ ((r >> 1) & 3)) << 4));
  }
#pragma unroll
  for (int n = 0; n < 12; n++) {
    int r = n * 16 + (lane & 15);
    boff[n] = (unsigned)(24576 + r * 64 + ((ch ^ ((r >> 1) & 3)) << 4));
  }

  f32x4 zero = {0.f, 0.f, 0.f, 0.f};
  f32x4 acc[3][12];
#pragma unroll
  for (int m = 0; m < 3; m++)
#pragma unroll
    for (int n = 0; n < 12; n++) acc[m][n] = zero;

  // prologue: stage kk=0 into buf 0
  float4 bv[3][2];
#pragma unroll
  for (int i = 0; i < 3; i++) gl_lds16(asrc[i], lds + adst[i]);
#pragma unroll
  for (int j = 0; j < 3; j++) { bv[j][0] = bsrc[j][0]; bv[j][1] = bsrc[j][1]; }
#pragma unroll
  for (int j = 0; j < 3; j++) {
    uint4 p;
    p.x = pk2(bv[j][0].x, bv[j][0].y); p.y = pk2(bv[j][0].z, bv[j][0].w);
    p.z = pk2(bv[j][1].x, bv[j][1].y); p.w = pk2(bv[j][1].z, bv[j][1].w);
    *(uint4*)(lds + bdst[j]) = p;
  }
  __syncthreads();

  int cur = 0;
  for (int kk = 0; kk < NK; kk++) {
    int nxt = cur ^ 1;
    if (kk + 1 < NK) {      // issue next-tile loads (latency hides under MFMA)
#pragma unroll
      for (int i = 0; i < 3; i++)
        gl_lds16(asrc[i] + (size_t)(kk + 1) * BK, lds + nxt * 12288 + adst[i]);
#pragma unroll
      for (int j = 0; j < 3; j++) {
        bv[j][0] = bsrc[j][(kk + 1) * 8];
        bv[j][1] = bsrc[j][(kk + 1) * 8 + 1];
      }
    }
    const unsigned char* Ab = lds + cur * 12288;
    short8 a[3];
#pragma unroll
    for (int m = 0; m < 3; m++) a[m] = *(const short8*)(Ab + aoff[m]);
    __builtin_amdgcn_s_setprio(1);
#pragma unroll
    for (int n = 0; n < 12; n++) {
      short8 b = *(const short8*)(lds + cur * 12288 + boff[n]);
#pragma unroll
      for (int m = 0; m < 3; m++)
        acc[m][n] = __builtin_amdgcn_mfma_f32_16x16x32_bf16(a[m], b, acc[m][n], 0, 0, 0);
    }
    __builtin_amdgcn_s_setprio(0);
    if (kk + 1 < NK) {      // pack B into next buffer (waits vmcnt via data dep)
#pragma unroll
      for (int j = 0; j < 3; j++) {
        uint4 p;
        p.x = pk2(bv[j][0].x, bv[j][0].y); p.y = pk2(bv[j][0].z, bv[j][0].w);
        p.z = pk2(bv[j][1].x, bv[j][1].y); p.w = pk2(bv[j][1].z, bv[j][1].w);
        *(uint4*)(lds + nxt * 12288 + bdst[j]) = p;
      }
    }
    __syncthreads();        // drains vmcnt (gload_lds) + lgkm before barrier
    cur = nxt;
  }

  // epilogue: bias + SwiGLU, store act bf16
  int colL = lane & 15, rq = lane >> 4;
#pragma unroll
  for (int m = 0; m < 3; m++) {
    int row0 = rowbase + wv * 48 + m * 16 + rq * 4;
#pragma unroll
    for (int n = 0; n < 6; n++) {
      int col = ct * 96 + n * 16 + colL;
      float bg = b1[(size_t)e * (2 * H_DIM) + col];
      float bl = b1[(size_t)e * (2 * H_DIM) + H_DIM + col];
#pragma unroll
      for (int j = 0; j < 4; j++) {
        float g = acc[m][n][j] + bg;
        float l = acc[m][n + 6][j] + bl;
        float s = 1.f / (1.f + __expf(-ALPHA * g));
        act[(size_t)(row0 + j) * H_DIM + col] = f2bf(g * s * (l + 1.f));
      }
    }
  }
}

// ---------------- K4: grouped gemm2 + bias, weighted atomic scatter ----------------
__global__ __launch_bounds__(256, 2) void k_gemm2(
    const unsigned short* __restrict__ act,
    const float* __restrict__ w2, const float* __restrict__ b2,
    const int* __restrict__ perm_tok, const float* __restrict__ perm_w,
    const int* __restrict__ d_off,
    float* __restrict__ out)
{
  __shared__ __align__(16) unsigned char lds[49152];
  __shared__ int stok[PADM]; __shared__ float swt[PADM];
  const int total = d_off[16];
  int bid = blockIdx.x;
  int wg = (bid & 7) * (G2 / 8) + (bid >> 3);
  int ct = wg / MAX_RT, rt = wg % MAX_RT;
  int rowbase = rt * PADM;
  if (rowbase >= total) return;
  int e = 0;
#pragma unroll
  for (int q = 0; q < E_NUM; q++) if (d_off[q + 1] <= rowbase) e = q + 1;

  int tid = threadIdx.x, lane = tid & 63, wv = tid >> 6;
  if (tid < PADM) { stok[tid] = perm_tok[rowbase + tid]; swt[tid] = perm_w[rowbase + tid]; }

  const unsigned short* asrc[3]; unsigned adst[3];
#pragma unroll
  for (int i = 0; i < 3; i++) {
    int cl = tid + 256 * i;
    int r = cl >> 2, c = cl & 3;
    int cs = c ^ ((r >> 1) & 3);
    asrc[i] = act + (size_t)(rowbase + r) * H_DIM + cs * 8;
    adst[i] = (unsigned)cl * 16;
  }
  const float4* bsrc[3]; unsigned bdst[3];
#pragma unroll
  for (int j = 0; j < 3; j++) {
    int idx = tid + 256 * j;
    int r = idx >> 2, c = idx & 3;
    size_t grow = (size_t)e * H_DIM + (size_t)(ct * PADM + r);
    bsrc[j] = (const float4*)(w2 + grow * H_DIM) + c * 2;
    bdst[j] = (unsigned)(24576 + r * 64 + ((c ^ ((r >> 1) & 3)) << 4));
  }

  int ch = lane >> 4;
  unsigned aoff[3], boff[12];
#pragma unroll
  for (int m = 0; m < 3; m++) {
    int r = wv * 48 + m * 16 + (lane & 15);
    aoff[m] = (unsigned)(r * 64 + ((ch ^ ((r >> 1) & 3)) << 4));
  }
#pragma unroll
  for (int n = 0; n < 12; n++) {
    int r = n * 16 + (lane & 15);
    boff[n] = (unsigned)(24576 + r * 64 + ((ch ^ ((r >> 1) & 3)) << 4));
  }

  f32x4 zero = {0.f, 0.f, 0.f, 0.f};
  f32x4 acc[3][12];
#pragma unroll
  for (int m = 0; m < 3; m++)
#pragma unroll
    for (int n = 0; n < 12; n++) acc[m][n] = zero;

  float4 bv[3][2];
#pragma unroll
  for (int i = 0; i < 3; i++) gl_lds16(asrc[i], lds + adst[i]);
#pragma unroll
  for (int j = 0; j < 3; j++) { bv[j][0] = bsrc[j][0]; bv[j][1] = bsrc[j][1]; }
#pragma unroll
  for (int j = 0; j < 3; j++) {
    uint4 p;
    p.x = pk2(bv[j][0].x, bv[j][0].y); p.y = pk2(bv[j][0].z, bv[j][0].w);
    p.z = pk2(bv[j][1].x, bv[j][1].y); p.w = pk2(bv[j][1].z, bv[j][1].w);
    *(uint4*)(lds + bdst[j]) = p;
  }
  __syncthreads();

  int cur = 0;
  for (int kk = 0; kk < NK; kk++) {
    int nxt = cur ^ 1;
    if (kk + 1 < NK) {
#pragma unroll
      for (int i = 0; i < 3; i++)
        gl_lds16(asrc[i] + (size_t)(kk + 1) * BK, lds + nxt * 12288 + adst[i]);
#pragma unroll
      for (int j = 0; j < 3; j++) {
        bv[j][0] = bsrc[j][(kk + 1) * 8];
        bv[j][1] = bsrc[j][(kk + 1) * 8 + 1];
      }
    }
    const unsigned char* Ab = lds + cur * 12288;
    short8 a[3];
#pragma unroll
    for (int m = 0; m < 3; m++) a[m] = *(const short8*)(Ab + aoff[m]);
    __builtin_amdgcn_s_setprio(1);
#pragma unroll
    for (int n = 0; n < 12; n++) {
      short8 b = *(const short8*)(lds + cur * 12288 + boff[n]);
#pragma unroll
      for (int m = 0; m < 3; m++)
        acc[m][n] = __builtin_amdgcn_mfma_f32_16x16x32_bf16(a[m], b, acc[m][n], 0, 0, 0);
    }
    __builtin_amdgcn_s_setprio(0);
    if (kk + 1 < NK) {
#pragma unroll
      for (int j = 0; j < 3; j++) {
        uint4 p;
        p.x = pk2(bv[j][0].x, bv[j][0].y); p.y = pk2(bv[j][0].z, bv[j][0].w);
        p.z = pk2(bv[j][1].x, bv[j][1].y); p.w = pk2(bv[j][1].z, bv[j][1].w);
        *(uint4*)(lds + nxt * 12288 + bdst[j]) = p;
      }
    }
    __syncthreads();
    cur = nxt;
  }

  int colL = lane & 15, rq = lane >> 4;
#pragma unroll
  for (int m = 0; m < 3; m++) {
    int rl0 = wv * 48 + m * 16 + rq * 4;
#pragma unroll
    for (int n = 0; n < 12; n++) {
      int col = ct * PADM + n * 16 + colL;
      float bvv = b2[(size_t)e * H_DIM + col];
#pragma unroll
      for (int j = 0; j < 4; j++) {
        int rl = rl0 + j;
        float w = swt[rl];
        if (w != 0.f)
          atomicAdd(out + (size_t)stok[rl] * H_DIM + col, (acc[m][n][j] + bvv) * w);
      }
    }
  }
}

// ---------------- launch ----------------
extern "C" void kernel_launch(void* const* d_in, const int* in_sizes, int n_in,
                              void* d_out, int out_size, void* d_ws, size_t ws_size,
                              hipStream_t stream)
{
  const float* x      = (const float*)d_in[0];
  const float* norm_w = (const float*)d_in[1];
  const float* gate_w = (const float*)d_in[2];
  const float* gate_b = (const float*)d_in[3];
  const float* w1     = (const float*)d_in[4];
  const float* b1     = (const float*)d_in[5];
  const float* w2     = (const float*)d_in[6];
  const float* b2     = (const float*)d_in[7];
  float* out = (float*)d_out;
  char* ws = (char*)d_ws;

  // ws layout (~138.9 MB)
  unsigned short* t_bf16  = (unsigned short*)(ws);                    // 23,592,960
  unsigned short* act     = (unsigned short*)(ws + 23592960);         // 115,015,680
  int*            topk_id = (int*)(ws + 138608640);                   // 65,536
  float*          topk_w  = (float*)(ws + 138674176);                 // 65,536
  int*            perm_tk = (int*)(ws + 138739712);                   // 79,872
  float*          perm_w  = (float*)(ws + 138819584);                 // 79,872
  int*            counts  = (int*)(ws + 138899456);                   // 64
  int*            d_off   = (int*)(ws + 138899520);                   // 68

  hipMemsetAsync(counts, 0, 64, stream);
  hipLaunchKernelGGL(k_norm_gate, dim3(T_TOK), dim3(256), 0, stream,
                     x, norm_w, gate_w, gate_b, out, t_bf16, topk_id, topk_w, counts);
  hipLaunchKernelGGL(k_offsets, dim3(1), dim3(64), 0, stream, counts, d_off);
  hipLaunchKernelGGL(k_fill, dim3(16), dim3(256), 0, stream,
                     topk_id, topk_w, counts, d_off, perm_tk, perm_w);
  hipLaunchKernelGGL(k_gemm1, dim3(G1), dim3(256), 0, stream,
                     t_bf16, w1, b1, perm_tk, d_off, act);
  hipLaunchKernelGGL(k_gemm2, dim3(G2), dim3(256), 0, stream,
                     act, w2, b2, perm_tk, perm_w, d_off, out);
}